// Round 15
// baseline (471.670 us; speedup 1.0000x reference)
//
#include <hip/hip_runtime.h>

#define W 320
#define H 96
#define FS 96
#define BS 8
#define NPLANES 9
#define NCG 4              // channel groups (split-K)
#define CPG 24             // channels per group
#define YT 8               // rows per block tile (8 waves, one row each)
#define NTHREADS 512
#define HW (H * W)
#define CHUNK (BS * NPLANES * H * W)   // 2,211,840 floats per partial set

typedef float f4 __attribute__((ext_vector_type(4), aligned(4)));
typedef float f4a __attribute__((ext_vector_type(4), aligned(16)));

typedef const __attribute__((address_space(1))) void* gp1_t;
typedef __attribute__((address_space(3))) void*       lp3_t;

__device__ __forceinline__ void glds16(const float* g, float* l_) {
    __builtin_amdgcn_global_load_lds((gp1_t)g, (lp3_t)l_, 16, 0, 0);
}

// ---------------- kernel A: page-dense row-tile partials ----------------
// Block = (b, y8-tile, cg). Its 8 waves cover 8 CONSECUTIVE rows of the SAME
// channel at each step: two contiguous 10,240-B runs per channel-step (vs 16
// scattered 1.28-KB strips in R13). Pipeline is R13's HW-verified
// STAGE/COMP/vmcnt(4) double-buffer, FULLY HAND-UNROLLED — R14 post-mortem:
// rolling it into a runtime loop broke the counted-vmcnt accounting
// (absmax 0.17). Counted-waitcnt pipelines must be statically scheduled.
__global__ __launch_bounds__(NTHREADS)
void cost_volume_partial(const float* __restrict__ f1,
                         const float* __restrict__ f2,
                         float* __restrict__ ws)
{
    __shared__ float pool[8 * 1280];   // per-wave: 2 bufs x (320 f2 + 320 f1)

    const int t    = threadIdx.x;
    const int wv   = t >> 6;
    const int l    = t & 63;
    const int bx   = blockIdx.x;
    const int cg   = bx & 3;           // channel group 0..3
    const int rest = bx >> 2;
    const int y8   = rest % (H / YT);  // 0..11
    const int b    = rest / (H / YT);
    const int y    = y8 * YT + wv;

    const int x0 = 5 * l;              // output cols x0..x0+4 (64*5=320)
    const unsigned mlo = (l == 0)  ? 0u : ~0u;
    const unsigned mhi = (l == 63) ? 0u : ~0u;

    const size_t rowoff = ((size_t)(b * FS) * H + y) * W;
    const float* f1w = f1 + rowoff + (size_t)(cg * CPG) * HW;
    const float* f2w = f2 + rowoff + (size_t)(cg * CPG) * HW;

    float* const bufA = &pool[wv * 1280];
    float* const bufB = bufA + 640;

    float acc[5][9];
#pragma unroll
    for (int j = 0; j < 5; ++j)
#pragma unroll
        for (int p = 0; p < 9; ++p) acc[j][p] = 0.f;

#define STAGE(cc_, D_) do {                                                  \
    const float* f2c_ = f2w + (size_t)(cc_) * HW;                            \
    const float* f1c_ = f1w + (size_t)(cc_) * HW;                            \
    glds16(f2c_ + 4 * l, D_);                                                \
    glds16(f1c_ + 4 * l, D_ + 320);                                          \
    if (l < 16) {                                                            \
        glds16(f2c_ + 256 + 4 * l, D_ + 256);                                \
        glds16(f1c_ + 256 + 4 * l, D_ + 320 + 256);                          \
    }                                                                        \
} while (0)

#define COMP(D_) do {                                                        \
    const float* s2_ = D_;                                                   \
    const float* s1_ = D_ + 320;                                             \
    float wv_[13];                                                           \
    _Pragma("unroll")                                                        \
    for (int e = 0; e < 4; ++e) {                                            \
        const int col = x0 - 4 + e;                                          \
        const int cl  = col < 0 ? 0 : col;                                   \
        wv_[e] = __uint_as_float(__float_as_uint(s2_[cl]) & mlo);            \
    }                                                                        \
    _Pragma("unroll")                                                        \
    for (int e = 4; e < 9; ++e) wv_[e] = s2_[x0 - 4 + e];                    \
    _Pragma("unroll")                                                        \
    for (int e = 9; e < 13; ++e) {                                           \
        const int col = x0 - 4 + e;                                          \
        const int cl  = col > 319 ? 319 : col;                               \
        wv_[e] = __uint_as_float(__float_as_uint(s2_[cl]) & mhi);            \
    }                                                                        \
    float a_[5];                                                             \
    _Pragma("unroll")                                                        \
    for (int j = 0; j < 5; ++j) a_[j] = s1_[x0 + j];                         \
    _Pragma("unroll")                                                        \
    for (int j = 0; j < 5; ++j)                                              \
        _Pragma("unroll")                                                    \
        for (int p = 0; p < 9; ++p)                                          \
            acc[j][p] = fmaf(a_[j], wv_[j + 8 - p], acc[j][p]);              \
} while (0)

#define VW4() asm volatile("s_waitcnt vmcnt(4)" ::: "memory")
#define VW0() asm volatile("s_waitcnt vmcnt(0)" ::: "memory")

    // Hand-unrolled: at every VW4 exactly 8 DMA issues are outstanding
    // (4 old-buffer FIFO-retired by the wait, 4 new in flight).
    STAGE(0, bufA);
    STAGE(1, bufB);
    VW4();  COMP(bufA);  STAGE(2,  bufA);   // ch0
    VW4();  COMP(bufB);  STAGE(3,  bufB);   // ch1
    VW4();  COMP(bufA);  STAGE(4,  bufA);   // ch2
    VW4();  COMP(bufB);  STAGE(5,  bufB);   // ch3
    VW4();  COMP(bufA);  STAGE(6,  bufA);   // ch4
    VW4();  COMP(bufB);  STAGE(7,  bufB);   // ch5
    VW4();  COMP(bufA);  STAGE(8,  bufA);   // ch6
    VW4();  COMP(bufB);  STAGE(9,  bufB);   // ch7
    VW4();  COMP(bufA);  STAGE(10, bufA);   // ch8
    VW4();  COMP(bufB);  STAGE(11, bufB);   // ch9
    VW4();  COMP(bufA);  STAGE(12, bufA);   // ch10
    VW4();  COMP(bufB);  STAGE(13, bufB);   // ch11
    VW4();  COMP(bufA);  STAGE(14, bufA);   // ch12
    VW4();  COMP(bufB);  STAGE(15, bufB);   // ch13
    VW4();  COMP(bufA);  STAGE(16, bufA);   // ch14
    VW4();  COMP(bufB);  STAGE(17, bufB);   // ch15
    VW4();  COMP(bufA);  STAGE(18, bufA);   // ch16
    VW4();  COMP(bufB);  STAGE(19, bufB);   // ch17
    VW4();  COMP(bufA);  STAGE(20, bufA);   // ch18
    VW4();  COMP(bufB);  STAGE(21, bufB);   // ch19
    VW4();  COMP(bufA);  STAGE(22, bufA);   // ch20
    VW4();  COMP(bufB);  STAGE(23, bufB);   // ch21
    VW4();  COMP(bufA);                     // ch22
    VW0();  COMP(bufB);                     // ch23 (all DMA drained)

#undef STAGE
#undef COMP
#undef VW4
#undef VW0

    // wave owns slice (cg,b,y) exclusively: direct write, pre-scaled
    const float scale = 1.0f / (float)FS;
    float* wsb = ws + (size_t)cg * CHUNK;
#pragma unroll
    for (int p = 0; p < 9; ++p) {
        float* op = wsb + (((size_t)(b * NPLANES + p)) * H + y) * W + x0;
        f4 v;
        v.x = acc[0][p] * scale;
        v.y = acc[1][p] * scale;
        v.z = acc[2][p] * scale;
        v.w = acc[3][p] * scale;
        *(f4*)op = v;
        op[4] = acc[4][p] * scale;
    }
}

// ---------------- kernel B: sum 4 partials -> out (R11-verified) --------
__global__ __launch_bounds__(256)
void cost_volume_reduce(const float* __restrict__ ws, float* __restrict__ out)
{
    const size_t i4 = ((size_t)blockIdx.x * 256 + threadIdx.x) * 4;
    f4a a = *(const f4a*)(ws + i4);
    a += *(const f4a*)(ws + (size_t)1 * CHUNK + i4);
    a += *(const f4a*)(ws + (size_t)2 * CHUNK + i4);
    a += *(const f4a*)(ws + (size_t)3 * CHUNK + i4);
    *(f4a*)(out + i4) = a;
}

// ---------------- fallback: verified round-10 fused kernel --------------
#define RSTRIDE 45
__global__ __launch_bounds__(512)
void cost_volume_fused(const float* __restrict__ f1,
                       const float* __restrict__ f2,
                       float* __restrict__ out)
{
    __shared__ float red[4 * 64 * RSTRIDE];
    const int t   = threadIdx.x;
    const int wv  = t >> 6;
    const int l   = t & 63;
    const int row = blockIdx.x;
    const int b   = row / H;
    const int y   = row % H;
    const int x0 = 5 * l;
    const int o0 = (x0 - 4 < 0)   ? 0   : x0 - 4;
    const int o2 = (x0 + 4 > 316) ? 316 : x0 + 4;
    const int o3 = (x0 + 8 > 319) ? 319 : x0 + 8;
    const unsigned mlo = (l == 0)  ? 0u : ~0u;
    const unsigned mhi = (l == 63) ? 0u : ~0u;
    const bool hi = (l == 63);
    const size_t rowoff = ((size_t)(b * FS) * H + y) * W;
    const float* f1w = f1 + rowoff + (size_t)(wv * 12) * HW;
    const float* f2w = f2 + rowoff + (size_t)(wv * 12) * HW;
    float acc[5][9];
#pragma unroll
    for (int j = 0; j < 5; ++j)
#pragma unroll
        for (int p = 0; p < 9; ++p) acc[j][p] = 0.f;
#pragma unroll 4
    for (int cc = 0; cc < 12; ++cc) {
        const float* f1c = f1w + (size_t)cc * HW;
        const float* f2c = f2w + (size_t)cc * HW;
        const f4   q0 = *(const f4*)(f2c + o0);
        const f4   q1 = *(const f4*)(f2c + x0);
        const f4   q2 = *(const f4*)(f2c + o2);
        const float s3 = f2c[o3];
        const f4   af = *(const f4*)(f1c + x0);
        const float a4 = f1c[x0 + 4];
        float w_[13];
        w_[0]  = __uint_as_float(__float_as_uint(q0.x) & mlo);
        w_[1]  = __uint_as_float(__float_as_uint(q0.y) & mlo);
        w_[2]  = __uint_as_float(__float_as_uint(q0.z) & mlo);
        w_[3]  = __uint_as_float(__float_as_uint(q0.w) & mlo);
        w_[4]  = q1.x;  w_[5] = q1.y;  w_[6] = q1.z;  w_[7] = q1.w;
        w_[8]  = hi ? q2.w : q2.x;
        w_[9]  = __uint_as_float(__float_as_uint(q2.y) & mhi);
        w_[10] = __uint_as_float(__float_as_uint(q2.z) & mhi);
        w_[11] = __uint_as_float(__float_as_uint(q2.w) & mhi);
        w_[12] = __uint_as_float(__float_as_uint(s3)   & mhi);
        const float a_[5] = { af.x, af.y, af.z, af.w, a4 };
#pragma unroll
        for (int j = 0; j < 5; ++j)
#pragma unroll
            for (int p = 0; p < 9; ++p)
                acc[j][p] = fmaf(a_[j], w_[j + 8 - p], acc[j][p]);
    }
#define PARK(slot_) do {                                                     \
    float* dst_ = &red[((slot_) * 64 + l) * RSTRIDE];                        \
    _Pragma("unroll")                                                        \
    for (int j = 0; j < 5; ++j)                                              \
        _Pragma("unroll")                                                    \
        for (int p = 0; p < 9; ++p) dst_[j * 9 + p] = acc[j][p];             \
} while (0)
#define GRAB(slot_) do {                                                     \
    const float* src_ = &red[((slot_) * 64 + l) * RSTRIDE];                  \
    _Pragma("unroll")                                                        \
    for (int j = 0; j < 5; ++j)                                              \
        _Pragma("unroll")                                                    \
        for (int p = 0; p < 9; ++p) acc[j][p] += src_[j * 9 + p];            \
} while (0)
    if (wv >= 4) PARK(wv - 4);
    __syncthreads();
    if (wv < 4) GRAB(wv);
    __syncthreads();
    if (wv == 2 || wv == 3) PARK(wv);
    __syncthreads();
    if (wv < 2) GRAB(wv + 2);
    __syncthreads();
    if (wv == 1) PARK(0);
    __syncthreads();
    if (wv == 0) {
        GRAB(0);
        const float scale = 1.0f / (float)FS;
#pragma unroll
        for (int p = 0; p < 9; ++p) {
            float* op = out + (((size_t)(b * NPLANES + p)) * H + y) * W + x0;
            f4 v;
            v.x = acc[0][p] * scale;
            v.y = acc[1][p] * scale;
            v.z = acc[2][p] * scale;
            v.w = acc[3][p] * scale;
            *(f4*)op = v;
            op[4] = acc[4][p] * scale;
        }
    }
#undef PARK
#undef GRAB
}

extern "C" void kernel_launch(void* const* d_in, const int* in_sizes, int n_in,
                              void* d_out, int out_size, void* d_ws, size_t ws_size,
                              hipStream_t stream) {
    (void)in_sizes; (void)n_in; (void)out_size;
    const float* f1 = (const float*)d_in[0];
    const float* f2 = (const float*)d_in[1];
    float* out = (float*)d_out;

    const size_t ws_need = (size_t)NCG * CHUNK * sizeof(float);   // 35.4 MB
    if (d_ws != nullptr && ws_size >= ws_need) {
        float* ws = (float*)d_ws;
        cost_volume_partial<<<dim3(BS * (H / YT) * NCG), dim3(NTHREADS), 0, stream>>>(f1, f2, ws);
        cost_volume_reduce<<<dim3(CHUNK / 4 / 256), dim3(256), 0, stream>>>(ws, out);
    } else {
        cost_volume_fused<<<dim3(BS * H), dim3(512), 0, stream>>>(f1, f2, out);
    }
}

// Round 17
// 208.469 us; speedup vs baseline: 2.2625x; 2.2625x over previous
//
#include <hip/hip_runtime.h>

#define W 320
#define H 96
#define FS 96
#define BS 8
#define NPLANES 9
#define CPW 24            // channels per wave (FS / 4 waves)
#define NTHREADS 256      // 4 waves per block, one (b,y) row per block
#define RSTRIDE 52        // LDS floats per lane slot (45 used, padded)

// 4-byte-aligned float4: x0 = 5*lane is only dword-aligned
typedef float f4 __attribute__((ext_vector_type(4), aligned(4)));

// R7 kernel (verified 79us, VGPR 72, no spill) with ONE change: all f1/f2
// reads are NON-TEMPORAL (nt flag -> stream past L3). 16 rounds established
// logical reads are served at ~2.4 TB/s from the L3-HIT path regardless of
// structure; the only 6.3 TB/s pattern measured on this chip (m13) streams
// from HBM. This tests whether the wall is the L3-hit service path.
__global__ __launch_bounds__(NTHREADS, 3)
void cost_volume_kernel(const float* __restrict__ f1,
                        const float* __restrict__ f2,
                        float* __restrict__ out)
{
    // end-reduction buffer only: waves 1..3 park 45 partials/lane
    __shared__ float red[3 * 64 * RSTRIDE];   // 39,936 B -> 3 blocks/CU

    const int t   = threadIdx.x;
    const int wv  = t >> 6;          // wave 0..3
    const int l   = t & 63;          // lane
    const int row = blockIdx.x;      // 0..767 = (b, y)
    const int b   = row / H;
    const int y   = row % H;

    // lane covers output cols x0..x0+4 (VX=5; 64*5 = 320 exactly)
    const int x0 = 5 * l;
    // f2 window: cols x0-4 .. x0+12, as 3 quads + 1 scalar with edge-clamped
    // addresses; clamped lanes' values zeroed by bitmask (AND, not mul:
    // clamped reads may be Inf/NaN).
    const int o0 = (x0 - 4 < 0)   ? 0   : x0 - 4;   // quad: e0..e3
    const int o2 = (x0 + 4 > 316) ? 316 : x0 + 4;   // quad: e8..e11
    const int o3 = (x0 + 8 > 319) ? 319 : x0 + 8;   // scalar: e12
    const unsigned mlo = (l == 0)  ? 0u : ~0u;  // lane 0: cols -4..-1 invalid
    const unsigned mhi = (l == 63) ? 0u : ~0u;  // lane 63: cols 320..323 invalid
    const bool hi = (l == 63);                  // lane 63: e8 (col 319) = q2.w

    const size_t rowoff = ((size_t)(b * FS) * H + y) * W;
    const float* f1w = f1 + rowoff + (size_t)(wv * CPW) * (H * W);
    const float* f2w = f2 + rowoff + (size_t)(wv * CPW) * (H * W);

    float acc[5][9];
#pragma unroll
    for (int j = 0; j < 5; ++j)
#pragma unroll
        for (int p = 0; p < 9; ++p) acc[j][p] = 0.f;

    // ---- streaming channel loop: no LDS, no barriers, pure load->FMA ----
#pragma unroll 6
    for (int cc = 0; cc < CPW; ++cc) {
        const float* f1c = f1w + (size_t)cc * (H * W);
        const float* f2c = f2w + (size_t)cc * (H * W);

        const f4   q0 = __builtin_nontemporal_load((const f4*)(f2c + o0));
        const f4   q1 = __builtin_nontemporal_load((const f4*)(f2c + x0));
        const f4   q2 = __builtin_nontemporal_load((const f4*)(f2c + o2));
        const float s3 = __builtin_nontemporal_load(f2c + o3);
        const f4   af = __builtin_nontemporal_load((const f4*)(f1c + x0));
        const float a4 = __builtin_nontemporal_load(f1c + x0 + 4);

        float w_[13];
        w_[0]  = __uint_as_float(__float_as_uint(q0.x) & mlo);
        w_[1]  = __uint_as_float(__float_as_uint(q0.y) & mlo);
        w_[2]  = __uint_as_float(__float_as_uint(q0.z) & mlo);
        w_[3]  = __uint_as_float(__float_as_uint(q0.w) & mlo);
        w_[4]  = q1.x;  w_[5] = q1.y;  w_[6] = q1.z;  w_[7] = q1.w;
        w_[8]  = hi ? q2.w : q2.x;   // lane63's q2 clamped to 316 -> col319=.w
        w_[9]  = __uint_as_float(__float_as_uint(q2.y) & mhi);
        w_[10] = __uint_as_float(__float_as_uint(q2.z) & mhi);
        w_[11] = __uint_as_float(__float_as_uint(q2.w) & mhi);
        w_[12] = __uint_as_float(__float_as_uint(s3)   & mhi);

        const float a_[5] = { af.x, af.y, af.z, af.w, a4 };

        // plane p <-> shift i = p-4; window index e = j + 8 - p
#pragma unroll
        for (int j = 0; j < 5; ++j)
#pragma unroll
            for (int p = 0; p < 9; ++p)
                acc[j][p] = fmaf(a_[j], w_[j + 8 - p], acc[j][p]);
    }

    // ---- single end-of-kernel combine: waves 1..3 -> LDS, wave 0 sums ----
    if (wv != 0) {
        float* dst = &red[((wv - 1) * 64 + l) * RSTRIDE];
#pragma unroll
        for (int j = 0; j < 5; ++j)
#pragma unroll
            for (int p = 0; p < 9; ++p)
                dst[j * 9 + p] = acc[j][p];
    }
    __syncthreads();
    if (wv == 0) {
#pragma unroll
        for (int u = 0; u < 3; ++u) {
            const float* src = &red[(u * 64 + l) * RSTRIDE];
#pragma unroll
            for (int j = 0; j < 5; ++j)
#pragma unroll
                for (int p = 0; p < 9; ++p)
                    acc[j][p] += src[j * 9 + p];
        }
        const float scale = 1.0f / (float)FS;
#pragma unroll
        for (int p = 0; p < 9; ++p) {
            float* op = out + (((size_t)(b * NPLANES + p)) * H + y) * W + x0;
            f4 v;
            v.x = acc[0][p] * scale;
            v.y = acc[1][p] * scale;
            v.z = acc[2][p] * scale;
            v.w = acc[3][p] * scale;
            *(f4*)op = v;
            op[4] = acc[4][p] * scale;
        }
    }
}

extern "C" void kernel_launch(void* const* d_in, const int* in_sizes, int n_in,
                              void* d_out, int out_size, void* d_ws, size_t ws_size,
                              hipStream_t stream) {
    (void)in_sizes; (void)n_in; (void)d_ws; (void)ws_size; (void)out_size;
    const float* f1 = (const float*)d_in[0];
    const float* f2 = (const float*)d_in[1];
    float* out = (float*)d_out;

    dim3 grid(BS * H);        // 768 blocks x 4 waves = 12 waves/CU
    dim3 block(NTHREADS);
    cost_volume_kernel<<<grid, block, 0, stream>>>(f1, f2, out);
}

// Round 18
// 206.422 us; speedup vs baseline: 2.2850x; 1.0099x over previous
//
#include <hip/hip_runtime.h>

#define W 320
#define H 96
#define FS 96
#define BS 8
#define NPLANES 9
#define CPW 12            // channels per wave (FS / 8 waves)
#define NTHREADS 512      // 8 waves per block, one (b,y) row per block
#define RSTRIDE 45        // contiguous odd stride -> 2-way bank alias (free)

// 4-byte-aligned float4: x0 = 5*lane is only dword-aligned
typedef float f4 __attribute__((ext_vector_type(4), aligned(4)));

// R10 structure (verified: VGPR 56, no spill, passed @81.7us) + R17's
// nontemporal loads (verified: broke the 79us L3-hit-path plateau -> 60us).
// Theory: NT removed the ~2.4 TB/s L3-hit rate wall; now concurrency binds
// (R17 ran only 12 waves/CU). This doubles waves/CU to 24.
__global__ __launch_bounds__(NTHREADS)   // NO min-waves clamp (R8 lesson)
void cost_volume_kernel(const float* __restrict__ f1,
                        const float* __restrict__ f2,
                        float* __restrict__ out)
{
    // 4 reduction slots x 64 lanes x 45 floats = 46,080 B -> 3 blocks/CU
    __shared__ float red[4 * 64 * RSTRIDE];

    const int t   = threadIdx.x;
    const int wv  = t >> 6;          // wave 0..7
    const int l   = t & 63;          // lane
    const int row = blockIdx.x;      // 0..767 = (b, y)
    const int b   = row / H;
    const int y   = row % H;

    // lane covers output cols x0..x0+4 (VX=5; 64*5 = 320 exactly)
    const int x0 = 5 * l;
    // f2 window: cols x0-4 .. x0+12, as 3 quads + 1 scalar with edge-clamped
    // addresses; clamped lanes' values zeroed by bitmask (AND, not mul:
    // clamped reads may be Inf/NaN).
    const int o0 = (x0 - 4 < 0)   ? 0   : x0 - 4;   // quad: e0..e3
    const int o2 = (x0 + 4 > 316) ? 316 : x0 + 4;   // quad: e8..e11
    const int o3 = (x0 + 8 > 319) ? 319 : x0 + 8;   // scalar: e12
    const unsigned mlo = (l == 0)  ? 0u : ~0u;
    const unsigned mhi = (l == 63) ? 0u : ~0u;
    const bool hi = (l == 63);                      // e8 (col 319) = q2.w

    const size_t rowoff = ((size_t)(b * FS) * H + y) * W;
    const float* f1w = f1 + rowoff + (size_t)(wv * CPW) * (H * W);
    const float* f2w = f2 + rowoff + (size_t)(wv * CPW) * (H * W);

    float acc[5][9];
#pragma unroll
    for (int j = 0; j < 5; ++j)
#pragma unroll
        for (int p = 0; p < 9; ++p) acc[j][p] = 0.f;

    // ---- streaming channel loop: no LDS, no barriers, NT load->FMA ----
#pragma unroll 4
    for (int cc = 0; cc < CPW; ++cc) {
        const float* f1c = f1w + (size_t)cc * (H * W);
        const float* f2c = f2w + (size_t)cc * (H * W);

        const f4   q0 = __builtin_nontemporal_load((const f4*)(f2c + o0));
        const f4   q1 = __builtin_nontemporal_load((const f4*)(f2c + x0));
        const f4   q2 = __builtin_nontemporal_load((const f4*)(f2c + o2));
        const float s3 = __builtin_nontemporal_load(f2c + o3);
        const f4   af = __builtin_nontemporal_load((const f4*)(f1c + x0));
        const float a4 = __builtin_nontemporal_load(f1c + x0 + 4);

        float w_[13];
        w_[0]  = __uint_as_float(__float_as_uint(q0.x) & mlo);
        w_[1]  = __uint_as_float(__float_as_uint(q0.y) & mlo);
        w_[2]  = __uint_as_float(__float_as_uint(q0.z) & mlo);
        w_[3]  = __uint_as_float(__float_as_uint(q0.w) & mlo);
        w_[4]  = q1.x;  w_[5] = q1.y;  w_[6] = q1.z;  w_[7] = q1.w;
        w_[8]  = hi ? q2.w : q2.x;   // lane63's q2 clamped to 316 -> col319=.w
        w_[9]  = __uint_as_float(__float_as_uint(q2.y) & mhi);
        w_[10] = __uint_as_float(__float_as_uint(q2.z) & mhi);
        w_[11] = __uint_as_float(__float_as_uint(q2.w) & mhi);
        w_[12] = __uint_as_float(__float_as_uint(s3)   & mhi);

        const float a_[5] = { af.x, af.y, af.z, af.w, a4 };

        // plane p <-> shift i = p-4; window index e = j + 8 - p
#pragma unroll
        for (int j = 0; j < 5; ++j)
#pragma unroll
            for (int p = 0; p < 9; ++p)
                acc[j][p] = fmaf(a_[j], w_[j + 8 - p], acc[j][p]);
    }

    // ---- 3-phase LDS tree reduction: 8 waves -> wave 0 (R10-verified) ----
#define PARK(slot_) do {                                                     \
    float* dst_ = &red[((slot_) * 64 + l) * RSTRIDE];                        \
    _Pragma("unroll")                                                        \
    for (int j = 0; j < 5; ++j)                                              \
        _Pragma("unroll")                                                    \
        for (int p = 0; p < 9; ++p) dst_[j * 9 + p] = acc[j][p];             \
} while (0)

#define GRAB(slot_) do {                                                     \
    const float* src_ = &red[((slot_) * 64 + l) * RSTRIDE];                  \
    _Pragma("unroll")                                                        \
    for (int j = 0; j < 5; ++j)                                              \
        _Pragma("unroll")                                                    \
        for (int p = 0; p < 9; ++p) acc[j][p] += src_[j * 9 + p];            \
} while (0)

    if (wv >= 4) PARK(wv - 4);
    __syncthreads();
    if (wv < 4) GRAB(wv);
    __syncthreads();                 // anti-dep: reads done before re-write
    if (wv == 2 || wv == 3) PARK(wv);
    __syncthreads();
    if (wv < 2) GRAB(wv + 2);
    __syncthreads();
    if (wv == 1) PARK(0);
    __syncthreads();
    if (wv == 0) {
        GRAB(0);
        const float scale = 1.0f / (float)FS;
#pragma unroll
        for (int p = 0; p < 9; ++p) {
            float* op = out + (((size_t)(b * NPLANES + p)) * H + y) * W + x0;
            f4 v;
            v.x = acc[0][p] * scale;
            v.y = acc[1][p] * scale;
            v.z = acc[2][p] * scale;
            v.w = acc[3][p] * scale;
            *(f4*)op = v;
            op[4] = acc[4][p] * scale;
        }
    }

#undef PARK
#undef GRAB
}

extern "C" void kernel_launch(void* const* d_in, const int* in_sizes, int n_in,
                              void* d_out, int out_size, void* d_ws, size_t ws_size,
                              hipStream_t stream) {
    (void)in_sizes; (void)n_in; (void)d_ws; (void)ws_size; (void)out_size;
    const float* f1 = (const float*)d_in[0];
    const float* f2 = (const float*)d_in[1];
    float* out = (float*)d_out;

    dim3 grid(BS * H);        // 768 blocks x 8 waves = 24 waves/CU target
    dim3 block(NTHREADS);
    cost_volume_kernel<<<grid, block, 0, stream>>>(f1, f2, out);
}